// Round 9
// baseline (302.109 us; speedup 1.0000x reference)
//
#include <hip/hip_runtime.h>

// Problem constants (match reference)
#define B_   16
#define N_   65536
#define G_   64
#define M_   (N_ + G_)       // 65600 rois per batch
#define R_   128             // ROIS_PER_IMAGE
#define FGP  32              // FG_PER_IMAGE
#define NB_  16384           // buckets over u_perm in [0,1)
#define NROW_ 32             // (batch, class) rows
#define FW_  (NB_ / 32)      // flag words per row = 512
#define TPB_  256
#define NTAIL_ 256           // tail grid: 256 blocks on 256 CUs -> co-resident

// ---------------------------------------------------------------------------
// K0: zero hist+flags+barrier; GT table (poisoned gt_zero rows) + jmax.
// ---------------------------------------------------------------------------
__global__ void prep_kernel(const float* __restrict__ gt_boxes,
                            int*    __restrict__ zbase,   // hist..flags..bar
                            float4* __restrict__ gt4,
                            float*  __restrict__ garea,
                            int*    __restrict__ jmax)
{
    const int gid = blockIdx.x * blockDim.x + threadIdx.x;
    const int total = NROW_ * NB_ + NROW_ * FW_ + 2;      // hist + flags + bar
    for (int idx = gid; idx < total; idx += gridDim.x * blockDim.x) zbase[idx] = 0;
    if (gid < B_ * G_) {
        int b = gid >> 6, j = gid & 63;
        const float* g = gt_boxes + gid * 6;
        float x1 = g[0], y1 = g[1], x2 = g[2], y2 = g[3];
        float gw = x2 - x1 + 1.0f, gh = y2 - y1 + 1.0f;
        bool gz = (gw == 1.0f) && (gh == 1.0f);
        gt4[gid] = gz ? make_float4(3.0e8f, 3.0e8f, -3.0e8f, -3.0e8f)
                      : make_float4(x1, y1, x2, y2);
        garea[gid] = gw * gh;                     // == 1.0 for gz rows
        unsigned long long alive = __ballot(!gz); // lane == j
        if (j == 0) { int last = 63 - __clzll(alive); jmax[b] = (last + 8) & ~7; }
    }
}

// ---------------------------------------------------------------------------
// K1: per-roi rational IoU max (exact Dekker two-product lex compare),
//     one IEEE divide -> bit-exact max; classification + bucket histogram.
//     (identical numerics to the passing R6 kernel)
// ---------------------------------------------------------------------------
__global__ void iou_kernel(const float* __restrict__ all_rois,
                           const float* __restrict__ gt_boxes,
                           const float4* __restrict__ gt4,
                           const float*  __restrict__ garea,
                           const int*    __restrict__ jmax,
                           const float*  __restrict__ u_perm,
                           unsigned*     __restrict__ packed,
                           int*          __restrict__ hist)
{
    __shared__ float4 sg[G_];
    __shared__ float  sa[G_];
    const int b   = blockIdx.y;
    const int tid = threadIdx.x;
    if (tid < G_) { sg[tid] = gt4[b * G_ + tid]; sa[tid] = garea[b * G_ + tid]; }
    __syncthreads();

    const int i = blockIdx.x * blockDim.x + tid;
    if (i >= M_) return;

    float x1, y1, x2, y2;
    if (i < N_) {
        const float* p = all_rois + ((size_t)b * N_ + i) * 5;
        x1 = p[1]; y1 = p[2]; x2 = p[3]; y2 = p[4];
    } else {
        const float* p = gt_boxes + (b * G_ + (i - N_)) * 6;
        x1 = p[0]; y1 = p[1]; x2 = p[2]; y2 = p[3];
    }
    float aw = x2 - x1 + 1.0f, ah = y2 - y1 + 1.0f;
    float area_a = aw * ah;
    bool  a_zero = (aw == 1.0f) && (ah == 1.0f);

    const int jm = jmax[b];
    float ib = 0.0f, ub = 1.0f;              // rational best = 0/1
    for (int jj = 0; jj < jm; jj += 8) {
        #pragma unroll
        for (int kk = 0; kk < 8; ++kk) {
            const int j = jj + kk;
            const float4 g  = sg[j];
            const float  ga = sa[j];
            float iw  = fmaxf(fminf(x2, g.z) - fmaxf(x1, g.x) + 1.0f, 0.0f);
            float ih2 = fmaxf(fminf(y2, g.w) - fmaxf(y1, g.y) + 1.0f, 0.0f);
            float inter = iw * ih2;
            float uni   = area_a + ga - inter;        // > 0 always
            float hi1 = inter * ub, lo1 = fmaf(inter, ub, -hi1);
            float hi2 = ib * uni,   lo2 = fmaf(ib, uni, -hi2);
            bool gt = (hi1 > hi2) || ((hi1 == hi2) && (lo1 > lo2));  // exact
            if (gt) { ib = inter; ub = uni; }         // strict >: first wins
        }
    }
    float best = ib / ub;        // one IEEE divide: bit-exact ref max
    if (a_zero) best = -1.0f;

    bool fg = best >= 0.7f;
    bool bg = best < 0.3f;       // == ((mo<0.3)&(mo>=0)) | (mo<0)
    unsigned pk = 0xFFFFFFFFu;
    if (fg || bg) {
        int cls = fg ? 0 : 1;
        float u = u_perm[(size_t)b * M_ + i];
        int bucket = min(max((int)(u * (float)NB_), 0), NB_ - 1);
        pk = ((unsigned)cls << 16) | (unsigned)bucket;
        atomicAdd(&hist[(size_t)(b * 2 + cls) * NB_ + bucket], 1);
    }
    packed[(size_t)b * M_ + i] = pk;
}

// ---------------------------------------------------------------------------
// Device-scope epoch barrier for the persistent tail kernel.
// A: arrival counter (self-resets each epoch). R: monotone release epoch.
// Both zeroed by prep_kernel each launch -> replay-safe.
// ---------------------------------------------------------------------------
__device__ __forceinline__ void gsync(int* A, int* R, int epoch, int tid)
{
    __threadfence();
    __syncthreads();
    if (tid == 0) {
        int a = __hip_atomic_fetch_add(A, 1, __ATOMIC_ACQ_REL, __HIP_MEMORY_SCOPE_AGENT);
        if (a == NTAIL_ - 1) {
            __hip_atomic_store(A, 0, __ATOMIC_RELAXED, __HIP_MEMORY_SCOPE_AGENT);
            __hip_atomic_store(R, epoch, __ATOMIC_RELEASE, __HIP_MEMORY_SCOPE_AGENT);
        } else {
            while (__hip_atomic_load(R, __ATOMIC_ACQUIRE, __HIP_MEMORY_SCOPE_AGENT) < epoch) {
                __builtin_amdgcn_s_sleep(1);
            }
        }
    }
    __syncthreads();
    __threadfence();
}

// ---------------------------------------------------------------------------
// K2 (persistent, 256 blocks): scan -> B1 -> flag -> B2 -> scatter -> B3 ->
// sample. picks + GT tile live in LDS of blocks 0..15 across phases.
// ---------------------------------------------------------------------------
__global__ __launch_bounds__(TPB_) void tail_kernel(
    const float* __restrict__ all_rois,
    const float* __restrict__ gt_boxes,
    const float4* __restrict__ gt4,
    const float*  __restrict__ garea,
    const float* __restrict__ u_perm,
    const float* __restrict__ u_fg,
    const float* __restrict__ u_bg,
    float*    __restrict__ out,
    int*      __restrict__ hist,     // counts -> excl prefix -> destroyed
    unsigned* __restrict__ flags,
    int*      __restrict__ buckets,  // NROW*M
    int*      __restrict__ coarse_g, // NROW*32
    int*      __restrict__ cnt_g,    // NROW
    int*      __restrict__ bar)      // A, R
{
    const int bk  = blockIdx.x;
    const int tid = threadIdx.x;
    int* A = bar;
    int* R = bar + 1;

    __shared__ float4 sg[G_];
    __shared__ float  sa[G_];
    __shared__ int    scLDS[64];     // coarse: fg row 0..31, bg row 32..63
    __shared__ int4   spick[R_];
    __shared__ int    swt[4], swb[4];

    // ---- Phase 1: exclusive scan of each row (blocks 0..31, row = bk) ----
    if (bk < NROW_) {
        const int row = bk;
        const int lane = tid & 63, w = tid >> 6;
        int4* h4 = (int4*)(hist + (size_t)row * NB_ + tid * 64);
        int run = 0;
        #pragma unroll
        for (int q = 0; q < 16; ++q) { int4 x4 = h4[q]; run += x4.x + x4.y + x4.z + x4.w; }
        int x = run;                                   // wave inclusive scan
        #pragma unroll
        for (int d = 1; d < 64; d <<= 1) {
            int y = __shfl_up(x, d);
            if (lane >= d) x += y;
        }
        if (lane == 63) swt[w] = x;
        __syncthreads();
        if (tid == 0) { int a = 0; for (int q = 0; q < 4; ++q) { swb[q] = a; a += swt[q]; } }
        __syncthreads();
        const int incl = swb[w] + x;                   // thread-inclusive
        int base = incl - run;                         // thread-exclusive
        if ((tid & 7) == 7) coarse_g[row * 32 + (tid >> 3)] = incl;  // 512-bin chunks
        if (tid == 255) cnt_g[row] = incl;
        #pragma unroll
        for (int q = 0; q < 16; ++q) {                 // second pass: write prefix
            int4 x4 = h4[q];
            int4 o;
            o.x = base; o.y = base + x4.x; o.z = o.y + x4.y; o.w = o.z + x4.z;
            base = o.w + x4.w;
            h4[q] = o;
        }
    }
    gsync(A, R, 1, tid);

    // ---- Phase 2: flag (blocks 0..15, one per batch) ----
    if (bk < B_) {
        const int bb = bk;
        if (tid < 64) {
            scLDS[tid] = coarse_g[bb * 64 + tid];      // rows 2bb, 2bb+1
            sg[tid] = gt4[bb * G_ + tid];              // GT tile for phase 4
            sa[tid] = garea[bb * G_ + tid];
        }
        __syncthreads();
        if (tid < R_) {
            const int pos = tid;
            const int fgn = cnt_g[bb * 2 + 0];
            const int bgn = cnt_g[bb * 2 + 1];
            const bool both    = (fgn > 0) && (bgn > 0);
            const bool only_fg = (fgn > 0) && (bgn == 0);
            const int fg_this  = both ? min(FGP, fgn) : (only_fg ? R_ : 0);
            const bool is_fg   = pos < fg_this;
            int cls, rank, cnum;
            if (is_fg) {
                cls = 0; cnum = fgn;
                if (only_fg) {
                    float uf = u_fg[bb * R_ + pos];
                    int kk = (int)(uf * (float)fgn);   // trunc toward zero
                    rank = min(max(kk, 0), max(fgn - 1, 0));
                } else {
                    rank = pos;
                }
            } else {
                cls = 1; cnum = bgn;
                float ubv = u_bg[bb * R_ + pos];
                int kk = (int)(ubv * (float)bgn);
                rank = min(max(kk, 0), max(bgn - 1, 0));
            }
            int4 p4 = make_int4(0, 0, 0, is_fg ? 1 : 0);   // cnum==0 sentinel
            if (cnum > 0) {
                const int row = bb * 2 + cls;
                const int* sce = scLDS + cls * 32;
                int c = 0;                     // first chunk with incl > rank
                while (c < 31 && sce[c] <= rank) ++c;
                const int* Er = hist + (size_t)row * NB_;
                int lo = c * 512, hi = c * 512 + 511;
                while (lo < hi) {              // max j with Er[j] <= rank
                    int mid = (lo + hi + 1) >> 1;
                    if (Er[mid] <= rank) lo = mid; else hi = mid - 1;
                }
                const int start = Er[lo];
                const int next  = (lo < NB_ - 1) ? Er[lo + 1] : cnum;
                atomicOr(&flags[row * FW_ + (lo >> 5)], 1u << (lo & 31));
                p4 = make_int4(start, next - start, rank - start, is_fg ? 1 : 0);
            }
            spick[pos] = p4;
        }
    }
    gsync(A, R, 2, tid);

    // ---- Phase 3: scatter flagged-bucket members (all blocks) ----
    {
        const int stride = NTAIL_ * TPB_;              // 65536
        for (int it = 0; it < 17; ++it) {
            const int flat = it * stride + bk * TPB_ + tid;
            if (flat >= B_ * M_) break;
            unsigned pkv = ((const unsigned*)buckets - 1 == nullptr) ? 0u : 0u; // (placeholder avoided)
            (void)pkv;
            unsigned pv = ((const unsigned* __restrict__)(const void*)0 == 0) ? 0u : 0u;
            (void)pv;
            // real read below (packed passed via buckets? no) -- see note
            break;
        }
    }
    // NOTE: packed pointer needed here; restructured below.
    gsync(A, R, 3, tid);
    // (Phase 3 real implementation moved before this gsync in tail_kernel2.)

    // ---- Phase 4: selection + gather + lazy argmax (blocks 0..15) ----
    if (bk < B_ && tid < R_) {
        const int bb  = bk;
        const int pos = tid;
        const int4 p4 = spick[pos];
        const bool is_fg = p4.w != 0;
        const int  cls   = is_fg ? 0 : 1;
        int keep = 0;                  // cnum==0 edge: argsort(all 2.0)[0] == 0
        if (p4.y > 0) {
            const int row = bb * 2 + cls;
            const int*   be = buckets + (size_t)row * M_ + p4.x;
            const float* up = u_perm + (size_t)bb * M_;
            const int cnt2 = p4.y, r = p4.z;
            for (int t2 = 0; t2 < cnt2; ++t2) {   // r-th smallest by (u, idx)
                int it2 = be[t2]; float ut = up[it2];
                int rk = 0;
                for (int s2 = 0; s2 < cnt2; ++s2) {
                    if (s2 == t2) continue;
                    int is2 = be[s2]; float us = up[is2];
                    if (us < ut || (us == ut && is2 < it2)) rk++;
                }
                if (rk == r) { keep = it2; break; }
            }
        }
        float ox1, oy1, ox2, oy2;
        if (keep < N_) {
            const float* p = all_rois + ((size_t)bb * N_ + keep) * 5;
            ox1 = p[1]; oy1 = p[2]; ox2 = p[3]; oy2 = p[4];
        } else {
            const float* p = gt_boxes + (bb * G_ + (keep - N_)) * 6;
            ox1 = p[0]; oy1 = p[1]; ox2 = p[2]; oy2 = p[3];
        }
        float* ro = out + ((size_t)bb * R_ + pos) * 5;
        ro[0] = (float)bb; ro[1] = ox1; ro[2] = oy1; ro[3] = ox2; ro[4] = oy2;

        float lab = 0.0f, tidv = -1.0f;
        if (is_fg) {
            float aw = ox2 - ox1 + 1.0f, ah = oy2 - oy1 + 1.0f;
            float area_a = aw * ah;
            float bestv = -1e30f;
            int   bi    = 0;
            for (int j = 0; j < G_; ++j) {
                const float4 g  = sg[j];
                const float  ga = sa[j];
                float iw  = fmaxf(fminf(ox2, g.z) - fmaxf(ox1, g.x) + 1.0f, 0.0f);
                float ih2 = fmaxf(fminf(oy2, g.w) - fmaxf(oy1, g.y) + 1.0f, 0.0f);
                float inter = iw * ih2;
                float ov = inter / (area_a + ga - inter);   // IEEE div
                if (ov > bestv) { bestv = ov; bi = j; }     // first-max
            }
            lab  = gt_boxes[(bb * G_ + bi) * 6 + 4];
            tidv = gt_boxes[(bb * G_ + bi) * 6 + 5];
        }
        out[(size_t)B_ * R_ * 5 + bb * R_ + pos] = lab;
        out[(size_t)B_ * R_ * 5 + (size_t)B_ * R_ + bb * R_ + pos] = tidv;
    }
}

// The scatter phase needs `packed`; cleaner: a second definition with the
// proper parameter. (tail_kernel above kept minimal; we actually launch
// tail2 below which includes packed and the real phase-3 body.)
__global__ __launch_bounds__(TPB_) void tail2_kernel(
    const float* __restrict__ all_rois,
    const float* __restrict__ gt_boxes,
    const float4* __restrict__ gt4,
    const float*  __restrict__ garea,
    const float* __restrict__ u_perm,
    const float* __restrict__ u_fg,
    const float* __restrict__ u_bg,
    const unsigned* __restrict__ packed,
    float*    __restrict__ out,
    int*      __restrict__ hist,
    unsigned* __restrict__ flags,
    int*      __restrict__ buckets,
    int*      __restrict__ coarse_g,
    int*      __restrict__ cnt_g,
    int*      __restrict__ bar)
{
    const int bk  = blockIdx.x;
    const int tid = threadIdx.x;
    int* A = bar;
    int* R = bar + 1;

    __shared__ float4 sg[G_];
    __shared__ float  sa[G_];
    __shared__ int    scLDS[64];
    __shared__ int4   spick[R_];
    __shared__ int    swt[4], swb[4];

    // ---- Phase 1: exclusive scan (blocks 0..31, row = bk) ----
    if (bk < NROW_) {
        const int row = bk;
        const int lane = tid & 63, w = tid >> 6;
        int4* h4 = (int4*)(hist + (size_t)row * NB_ + tid * 64);
        int run = 0;
        #pragma unroll
        for (int q = 0; q < 16; ++q) { int4 x4 = h4[q]; run += x4.x + x4.y + x4.z + x4.w; }
        int x = run;
        #pragma unroll
        for (int d = 1; d < 64; d <<= 1) {
            int y = __shfl_up(x, d);
            if (lane >= d) x += y;
        }
        if (lane == 63) swt[w] = x;
        __syncthreads();
        if (tid == 0) { int a = 0; for (int q = 0; q < 4; ++q) { swb[q] = a; a += swt[q]; } }
        __syncthreads();
        const int incl = swb[w] + x;
        int base = incl - run;
        if ((tid & 7) == 7) coarse_g[row * 32 + (tid >> 3)] = incl;
        if (tid == 255) cnt_g[row] = incl;
        #pragma unroll
        for (int q = 0; q < 16; ++q) {
            int4 x4 = h4[q];
            int4 o;
            o.x = base; o.y = base + x4.x; o.z = o.y + x4.y; o.w = o.z + x4.z;
            base = o.w + x4.w;
            h4[q] = o;
        }
    }
    gsync(A, R, 1, tid);

    // ---- Phase 2: flag (blocks 0..15) ----
    if (bk < B_) {
        const int bb = bk;
        if (tid < 64) {
            scLDS[tid] = coarse_g[bb * 64 + tid];
            sg[tid] = gt4[bb * G_ + tid];
            sa[tid] = garea[bb * G_ + tid];
        }
        __syncthreads();
        if (tid < R_) {
            const int pos = tid;
            const int fgn = cnt_g[bb * 2 + 0];
            const int bgn = cnt_g[bb * 2 + 1];
            const bool both    = (fgn > 0) && (bgn > 0);
            const bool only_fg = (fgn > 0) && (bgn == 0);
            const int fg_this  = both ? min(FGP, fgn) : (only_fg ? R_ : 0);
            const bool is_fg   = pos < fg_this;
            int cls, rank, cnum;
            if (is_fg) {
                cls = 0; cnum = fgn;
                if (only_fg) {
                    float uf = u_fg[bb * R_ + pos];
                    int kk = (int)(uf * (float)fgn);
                    rank = min(max(kk, 0), max(fgn - 1, 0));
                } else {
                    rank = pos;
                }
            } else {
                cls = 1; cnum = bgn;
                float ubv = u_bg[bb * R_ + pos];
                int kk = (int)(ubv * (float)bgn);
                rank = min(max(kk, 0), max(bgn - 1, 0));
            }
            int4 p4 = make_int4(0, 0, 0, is_fg ? 1 : 0);
            if (cnum > 0) {
                const int row = bb * 2 + cls;
                const int* sce = scLDS + cls * 32;
                int c = 0;
                while (c < 31 && sce[c] <= rank) ++c;
                const int* Er = hist + (size_t)row * NB_;
                int lo = c * 512, hi = c * 512 + 511;
                while (lo < hi) {
                    int mid = (lo + hi + 1) >> 1;
                    if (Er[mid] <= rank) lo = mid; else hi = mid - 1;
                }
                const int start = Er[lo];
                const int next  = (lo < NB_ - 1) ? Er[lo + 1] : cnum;
                atomicOr(&flags[row * FW_ + (lo >> 5)], 1u << (lo & 31));
                p4 = make_int4(start, next - start, rank - start, is_fg ? 1 : 0);
            }
            spick[pos] = p4;
        }
    }
    gsync(A, R, 2, tid);

    // ---- Phase 3: scatter flagged-bucket members (all blocks) ----
    {
        const int stride = NTAIL_ * TPB_;              // 65536
        #pragma unroll 1
        for (int it = 0; it < 17; ++it) {
            const int flat = it * stride + bk * TPB_ + tid;
            if (flat >= B_ * M_) break;
            unsigned pkv = packed[flat];
            if (pkv == 0xFFFFFFFFu) continue;
            const int b2 = flat / M_;
            const int il = flat - b2 * M_;
            const int cls = (int)(pkv >> 16), bucket = (int)(pkv & 0xFFFFu);
            const int row = b2 * 2 + cls;
            unsigned wd = flags[row * FW_ + (bucket >> 5)];
            if (!(wd & (1u << (bucket & 31)))) continue;
            int p = atomicAdd(&hist[(size_t)row * NB_ + bucket], 1);  // destructive
            buckets[(size_t)row * M_ + p] = il;
        }
    }
    gsync(A, R, 3, tid);

    // ---- Phase 4: selection + gather + lazy argmax (blocks 0..15) ----
    if (bk < B_ && tid < R_) {
        const int bb  = bk;
        const int pos = tid;
        const int4 p4 = spick[pos];
        const bool is_fg = p4.w != 0;
        const int  cls   = is_fg ? 0 : 1;
        int keep = 0;                  // cnum==0 edge: argsort(all 2.0)[0] == 0
        if (p4.y > 0) {
            const int row = bb * 2 + cls;
            const int*   be = buckets + (size_t)row * M_ + p4.x;
            const float* up = u_perm + (size_t)bb * M_;
            const int cnt2 = p4.y, r = p4.z;
            for (int t2 = 0; t2 < cnt2; ++t2) {   // r-th smallest by (u, idx)
                int it2 = be[t2]; float ut = up[it2];
                int rk = 0;
                for (int s2 = 0; s2 < cnt2; ++s2) {
                    if (s2 == t2) continue;
                    int is2 = be[s2]; float us = up[is2];
                    if (us < ut || (us == ut && is2 < it2)) rk++;
                }
                if (rk == r) { keep = it2; break; }
            }
        }
        float ox1, oy1, ox2, oy2;
        if (keep < N_) {
            const float* p = all_rois + ((size_t)bb * N_ + keep) * 5;
            ox1 = p[1]; oy1 = p[2]; ox2 = p[3]; oy2 = p[4];
        } else {
            const float* p = gt_boxes + (bb * G_ + (keep - N_)) * 6;
            ox1 = p[0]; oy1 = p[1]; ox2 = p[2]; oy2 = p[3];
        }
        float* ro = out + ((size_t)bb * R_ + pos) * 5;
        ro[0] = (float)bb; ro[1] = ox1; ro[2] = oy1; ro[3] = ox2; ro[4] = oy2;

        float lab = 0.0f, tidv = -1.0f;
        if (is_fg) {
            float aw = ox2 - ox1 + 1.0f, ah = oy2 - oy1 + 1.0f;
            float area_a = aw * ah;
            float bestv = -1e30f;
            int   bi    = 0;
            for (int j = 0; j < G_; ++j) {
                const float4 g  = sg[j];
                const float  ga = sa[j];
                float iw  = fmaxf(fminf(ox2, g.z) - fmaxf(ox1, g.x) + 1.0f, 0.0f);
                float ih2 = fmaxf(fminf(oy2, g.w) - fmaxf(oy1, g.y) + 1.0f, 0.0f);
                float inter = iw * ih2;
                float ov = inter / (area_a + ga - inter);   // IEEE div
                if (ov > bestv) { bestv = ov; bi = j; }     // first-max
            }
            lab  = gt_boxes[(bb * G_ + bi) * 6 + 4];
            tidv = gt_boxes[(bb * G_ + bi) * 6 + 5];
        }
        out[(size_t)B_ * R_ * 5 + bb * R_ + pos] = lab;
        out[(size_t)B_ * R_ * 5 + (size_t)B_ * R_ + bb * R_ + pos] = tidv;
    }
}

// ---------------------------------------------------------------------------
extern "C" void kernel_launch(void* const* d_in, const int* in_sizes, int n_in,
                              void* d_out, int out_size, void* d_ws, size_t ws_size,
                              hipStream_t stream)
{
    const float* all_rois = (const float*)d_in[0];
    const float* gt_boxes = (const float*)d_in[1];
    const float* u_perm   = (const float*)d_in[2];
    const float* u_fg     = (const float*)d_in[3];
    const float* u_bg     = (const float*)d_in[4];
    float* out = (float*)d_out;

    // workspace layout (4B elems); ~15 MB. hist, flags, bar contiguous (zeroed
    // together by prep). bar AFTER flags.
    int*      hist    = (int*)d_ws;                               // NROW*NB
    unsigned* flags   = (unsigned*)(hist + (size_t)NROW_ * NB_);  // NROW*FW
    int*      bar     = (int*)(flags + NROW_ * FW_);              // 2
    int*      coarse  = bar + 2;                                  // NROW*32
    int*      cnt     = coarse + NROW_ * 32;                      // NROW
    unsigned* packed  = (unsigned*)(cnt + NROW_ + 2);             // B*M
    int*      buckets = (int*)(packed + (size_t)B_ * M_);         // NROW*M
    float4*   gt4     = (float4*)(buckets + (size_t)NROW_ * M_);  // B*G
    float*    garea   = (float*)(gt4 + B_ * G_);                  // B*G
    int*      jmax    = (int*)(garea + B_ * G_);                  // B

    prep_kernel<<<512, TPB_, 0, stream>>>(gt_boxes, hist, gt4, garea, jmax);

    dim3 grid1((M_ + TPB_ - 1) / TPB_, B_);
    iou_kernel<<<grid1, TPB_, 0, stream>>>(all_rois, gt_boxes, gt4, garea, jmax,
                                           u_perm, packed, hist);

    tail2_kernel<<<NTAIL_, TPB_, 0, stream>>>(all_rois, gt_boxes, gt4, garea,
                                              u_perm, u_fg, u_bg, packed, out,
                                              hist, flags, buckets, coarse, cnt, bar);
}

// Round 10
// 97.106 us; speedup vs baseline: 3.1111x; 3.1111x over previous
//
#include <hip/hip_runtime.h>

// Problem constants (match reference)
#define B_   16
#define N_   65536
#define G_   64
#define M_   (N_ + G_)       // 65600 rois per batch
#define R_   128             // ROIS_PER_IMAGE
#define FGP  32              // FG_PER_IMAGE
#define NB_  16384           // buckets over u_perm in [0,1)
#define NCH_ 32              // coarse chunks per row
#define CHUNK_ (NB_ / NCH_)  // 512
#define NROW_ 32             // (batch, class) rows
#define FW_  (NB_ / 32)      // flag words per row = 512
#define TPB_  256

// ---------------------------------------------------------------------------
// K0: zero hist+flags (contiguous); GT table (poisoned gt_zero rows) + jmax.
// ---------------------------------------------------------------------------
__global__ void prep_kernel(const float* __restrict__ gt_boxes,
                            int*    __restrict__ zbase,   // hist..flags
                            float4* __restrict__ gt4,
                            float*  __restrict__ garea,
                            int*    __restrict__ jmax)
{
    const int gid = blockIdx.x * blockDim.x + threadIdx.x;
    const int total = NROW_ * NB_ + NROW_ * FW_;
    for (int idx = gid; idx < total; idx += gridDim.x * blockDim.x) zbase[idx] = 0;
    if (gid < B_ * G_) {
        int b = gid >> 6, j = gid & 63;
        const float* g = gt_boxes + gid * 6;
        float x1 = g[0], y1 = g[1], x2 = g[2], y2 = g[3];
        float gw = x2 - x1 + 1.0f, gh = y2 - y1 + 1.0f;
        bool gz = (gw == 1.0f) && (gh == 1.0f);
        gt4[gid] = gz ? make_float4(3.0e8f, 3.0e8f, -3.0e8f, -3.0e8f)
                      : make_float4(x1, y1, x2, y2);
        garea[gid] = gw * gh;                     // == 1.0 for gz rows
        unsigned long long alive = __ballot(!gz); // lane == j
        if (j == 0) { int last = 63 - __clzll(alive); jmax[b] = (last + 8) & ~7; }
    }
}

// ---------------------------------------------------------------------------
// K1: per-roi rational IoU max (exact Dekker two-product lex compare),
//     one IEEE divide -> bit-exact ref max; classification + bucket histogram.
//     (byte-identical numerics to the passing R6 kernel)
// ---------------------------------------------------------------------------
__global__ void iou_kernel(const float* __restrict__ all_rois,
                           const float* __restrict__ gt_boxes,
                           const float4* __restrict__ gt4,
                           const float*  __restrict__ garea,
                           const int*    __restrict__ jmax,
                           const float*  __restrict__ u_perm,
                           unsigned*     __restrict__ packed,
                           int*          __restrict__ hist)
{
    __shared__ float4 sg[G_];
    __shared__ float  sa[G_];
    const int b   = blockIdx.y;
    const int tid = threadIdx.x;
    if (tid < G_) { sg[tid] = gt4[b * G_ + tid]; sa[tid] = garea[b * G_ + tid]; }
    __syncthreads();

    const int i = blockIdx.x * blockDim.x + tid;
    if (i >= M_) return;

    float x1, y1, x2, y2;
    if (i < N_) {
        const float* p = all_rois + ((size_t)b * N_ + i) * 5;
        x1 = p[1]; y1 = p[2]; x2 = p[3]; y2 = p[4];
    } else {
        const float* p = gt_boxes + (b * G_ + (i - N_)) * 6;
        x1 = p[0]; y1 = p[1]; x2 = p[2]; y2 = p[3];
    }
    float aw = x2 - x1 + 1.0f, ah = y2 - y1 + 1.0f;
    float area_a = aw * ah;
    bool  a_zero = (aw == 1.0f) && (ah == 1.0f);

    const int jm = jmax[b];
    float ib = 0.0f, ub = 1.0f;              // rational best = 0/1
    for (int jj = 0; jj < jm; jj += 8) {
        #pragma unroll
        for (int kk = 0; kk < 8; ++kk) {
            const int j = jj + kk;
            const float4 g  = sg[j];
            const float  ga = sa[j];
            float iw  = fmaxf(fminf(x2, g.z) - fmaxf(x1, g.x) + 1.0f, 0.0f);
            float ih2 = fmaxf(fminf(y2, g.w) - fmaxf(y1, g.y) + 1.0f, 0.0f);
            float inter = iw * ih2;
            float uni   = area_a + ga - inter;        // > 0 always
            float hi1 = inter * ub, lo1 = fmaf(inter, ub, -hi1);
            float hi2 = ib * uni,   lo2 = fmaf(ib, uni, -hi2);
            bool gt = (hi1 > hi2) || ((hi1 == hi2) && (lo1 > lo2));  // exact
            if (gt) { ib = inter; ub = uni; }         // strict >: first wins
        }
    }
    float best = ib / ub;        // one IEEE divide: bit-exact ref max
    if (a_zero) best = -1.0f;

    bool fg = best >= 0.7f;
    bool bg = best < 0.3f;       // == ((mo<0.3)&(mo>=0)) | (mo<0)
    unsigned pk = 0xFFFFFFFFu;
    if (fg || bg) {
        int cls = fg ? 0 : 1;
        float u = u_perm[(size_t)b * M_ + i];
        int bucket = min(max((int)(u * (float)NB_), 0), NB_ - 1);
        pk = ((unsigned)cls << 16) | (unsigned)bucket;
        atomicAdd(&hist[(size_t)(b * 2 + cls) * NB_ + bucket], 1);
    }
    packed[(size_t)b * M_ + i] = pk;
}

// ---------------------------------------------------------------------------
// K2: 16 blocks x 512 threads. Each block: exclusive-scan BOTH rows of its
//     batch in place (wave shfl scan; coarse+cnt stay in LDS), then flag:
//     rank -> bucket (LDS coarse walk + binsearch in this block's freshly
//     written prefix -- __syncthreads gives intra-block global visibility),
//     atomicOr flag bit, store {start,cnt,r,is_fg} to pick.
// ---------------------------------------------------------------------------
__global__ __launch_bounds__(512) void scanflag_kernel(
    int*      __restrict__ hist,     // counts -> exclusive prefix (in place)
    unsigned* __restrict__ flags,
    int*      __restrict__ cnt_g,    // NROW row totals (for sample)
    const float* __restrict__ u_fg,
    const float* __restrict__ u_bg,
    int4*     __restrict__ pick)
{
    __shared__ int scoarse[2][NCH_];
    __shared__ int scnt[2];
    __shared__ int swt[2][8], swb[2][8];
    const int bb  = blockIdx.x;       // batch
    const int tid = threadIdx.x;      // 512
    const int lane = tid & 63, w = tid >> 6;

    for (int rr = 0; rr < 2; ++rr) {
        const int row = bb * 2 + rr;
        int4* h4 = (int4*)(hist + (size_t)row * NB_ + tid * 32);
        int v[32];
        #pragma unroll
        for (int q = 0; q < 8; ++q) {
            int4 x4 = h4[q];
            v[q*4] = x4.x; v[q*4+1] = x4.y; v[q*4+2] = x4.z; v[q*4+3] = x4.w;
        }
        int run = 0;
        #pragma unroll
        for (int q = 0; q < 32; ++q) { int x = v[q]; v[q] = run; run += x; }
        int x = run;                                   // wave inclusive scan
        #pragma unroll
        for (int d = 1; d < 64; d <<= 1) {
            int y = __shfl_up(x, d);
            if (lane >= d) x += y;
        }
        if (lane == 63) swt[rr][w] = x;
        __syncthreads();
        if (tid == 0) {
            int a = 0;
            #pragma unroll
            for (int q = 0; q < 8; ++q) { swb[rr][q] = a; a += swt[rr][q]; }
        }
        __syncthreads();
        const int incl  = swb[rr][w] + x;              // thread-inclusive
        const int texcl = incl - run;                  // thread-exclusive base
        #pragma unroll
        for (int q = 0; q < 8; ++q) {
            h4[q] = make_int4(v[q*4] + texcl, v[q*4+1] + texcl,
                              v[q*4+2] + texcl, v[q*4+3] + texcl);
        }
        if ((tid & 15) == 15) scoarse[rr][tid >> 4] = incl;  // 512-bin chunks
        if (tid == 511) { scnt[rr] = incl; cnt_g[row] = incl; }
    }
    __syncthreads();   // prefix writes + scoarse/scnt visible block-wide

    if (tid < R_) {
        const int pos = tid;
        const int fgn = scnt[0], bgn = scnt[1];
        const bool both    = (fgn > 0) && (bgn > 0);
        const bool only_fg = (fgn > 0) && (bgn == 0);
        const int fg_this  = both ? min(FGP, fgn) : (only_fg ? R_ : 0);
        const bool is_fg   = pos < fg_this;
        int cls, rank, cnum;
        if (is_fg) {
            cls = 0; cnum = fgn;
            if (only_fg) {
                float uf = u_fg[bb * R_ + pos];
                int kk = (int)(uf * (float)fgn);       // trunc toward zero
                rank = min(max(kk, 0), max(fgn - 1, 0));
            } else {
                rank = pos;
            }
        } else {
            cls = 1; cnum = bgn;
            float ubv = u_bg[bb * R_ + pos];
            int kk = (int)(ubv * (float)bgn);
            rank = min(max(kk, 0), max(bgn - 1, 0));
        }
        int4 p4 = make_int4(0, 0, 0, is_fg ? 1 : 0);   // cnum==0 sentinel
        if (cnum > 0) {
            const int row = bb * 2 + cls;
            const int* sce = scoarse[cls];
            int c = 0;                     // first chunk with incl > rank
            while (c < NCH_ - 1 && sce[c] <= rank) ++c;
            const int* Er = hist + (size_t)row * NB_;
            int lo = c * CHUNK_, hi = c * CHUNK_ + CHUNK_ - 1;
            while (lo < hi) {              // max j with Er[j] <= rank
                int mid = (lo + hi + 1) >> 1;
                if (Er[mid] <= rank) lo = mid; else hi = mid - 1;
            }
            const int start = Er[lo];
            const int next  = (lo < NB_ - 1) ? Er[lo + 1] : cnum;
            atomicOr(&flags[row * FW_ + (lo >> 5)], 1u << (lo & 31));
            p4 = make_int4(start, next - start, rank - start, is_fg ? 1 : 0);
        }
        pick[bb * R_ + pos] = p4;
    }
}

// ---------------------------------------------------------------------------
// K3: scatter ONLY elements whose bucket is flagged (~0.2%) -> tiny writes.
//     Destructive atomicAdd on the prefix is fine: picks carry start/cnt.
// ---------------------------------------------------------------------------
__global__ void scatter_kernel(const unsigned* __restrict__ packed,
                               const unsigned* __restrict__ flags,
                               int*            __restrict__ E,      // hist prefix
                               int*            __restrict__ buckets)
{
    const int b = blockIdx.y;
    const int i = blockIdx.x * blockDim.x + threadIdx.x;
    if (i >= M_) return;
    unsigned pk = packed[(size_t)b * M_ + i];
    if (pk == 0xFFFFFFFFu) return;
    const int cls = (int)(pk >> 16);
    const int bucket = (int)(pk & 0xFFFFu);
    const int row = b * 2 + cls;
    unsigned w = flags[row * FW_ + (bucket >> 5)];     // 64KB table: L2-hot
    if (!(w & (1u << (bucket & 31)))) return;
    int p = atomicAdd(&E[(size_t)row * NB_ + bucket], 1);
    buckets[(size_t)row * M_ + p] = i;
}

// ---------------------------------------------------------------------------
// K4: stable (u, idx) rank-selection among bucket members, gather outputs,
//     lazy argmax (reference divide semantics) for picked fg rois only.
// ---------------------------------------------------------------------------
__global__ void sample_kernel(const float* __restrict__ all_rois,
                              const float* __restrict__ gt_boxes,
                              const float4* __restrict__ gt4,
                              const float*  __restrict__ garea,
                              const float* __restrict__ u_perm,
                              const int*  __restrict__ cnt,
                              const int4* __restrict__ pick,
                              const int*  __restrict__ buckets,
                              float*      __restrict__ out)
{
    const int b   = blockIdx.x;
    const int pos = threadIdx.x;   // 128
    const int4 pk = pick[b * R_ + pos];
    const bool is_fg = pk.w != 0;
    const int  cls   = is_fg ? 0 : 1;

    int keep = 0;                  // cnum==0 edge: argsort(all 2.0)[0] == 0
    if (pk.y > 0) {
        const int row = b * 2 + cls;
        const int*   be = buckets + (size_t)row * M_ + pk.x;
        const float* up = u_perm + (size_t)b * M_;
        const int cnt2 = pk.y, r = pk.z;
        for (int t2 = 0; t2 < cnt2; ++t2) {   // r-th smallest by (u, idx)
            int it = be[t2]; float ut = up[it];
            int rk = 0;
            for (int s2 = 0; s2 < cnt2; ++s2) {
                if (s2 == t2) continue;
                int is2 = be[s2]; float us = up[is2];
                if (us < ut || (us == ut && is2 < it)) rk++;
            }
            if (rk == r) { keep = it; break; }
        }
    }

    float ox1, oy1, ox2, oy2;
    if (keep < N_) {
        const float* p = all_rois + ((size_t)b * N_ + keep) * 5;
        ox1 = p[1]; oy1 = p[2]; ox2 = p[3]; oy2 = p[4];
    } else {
        const float* p = gt_boxes + (b * G_ + (keep - N_)) * 6;
        ox1 = p[0]; oy1 = p[1]; ox2 = p[2]; oy2 = p[3];
    }
    float* ro = out + ((size_t)b * R_ + pos) * 5;
    ro[0] = (float)b; ro[1] = ox1; ro[2] = oy1; ro[3] = ox2; ro[4] = oy2;

    float lab = 0.0f, tidv = -1.0f;
    if (is_fg) {
        float aw = ox2 - ox1 + 1.0f, ah = oy2 - oy1 + 1.0f;
        float area_a = aw * ah;
        float bestv = -1e30f;
        int   bi    = 0;
        for (int j = 0; j < G_; ++j) {
            const float4 g  = gt4[b * G_ + j];
            const float  ga = garea[b * G_ + j];
            float iw  = fmaxf(fminf(ox2, g.z) - fmaxf(ox1, g.x) + 1.0f, 0.0f);
            float ih2 = fmaxf(fminf(oy2, g.w) - fmaxf(oy1, g.y) + 1.0f, 0.0f);
            float inter = iw * ih2;
            float ov = inter / (area_a + ga - inter);   // IEEE div
            if (ov > bestv) { bestv = ov; bi = j; }     // first-max
        }
        lab  = gt_boxes[(b * G_ + bi) * 6 + 4];
        tidv = gt_boxes[(b * G_ + bi) * 6 + 5];
    }
    out[(size_t)B_ * R_ * 5 + b * R_ + pos] = lab;
    out[(size_t)B_ * R_ * 5 + (size_t)B_ * R_ + b * R_ + pos] = tidv;
}

// ---------------------------------------------------------------------------
extern "C" void kernel_launch(void* const* d_in, const int* in_sizes, int n_in,
                              void* d_out, int out_size, void* d_ws, size_t ws_size,
                              hipStream_t stream)
{
    const float* all_rois = (const float*)d_in[0];
    const float* gt_boxes = (const float*)d_in[1];
    const float* u_perm   = (const float*)d_in[2];
    const float* u_fg     = (const float*)d_in[3];
    const float* u_bg     = (const float*)d_in[4];
    float* out = (float*)d_out;

    // workspace layout (4B elems); ~14.8 MB. hist+flags contiguous (zeroed
    // together in prep). pick/gt4 offsets stay 16B-aligned.
    int*      hist    = (int*)d_ws;                               // NROW*NB
    unsigned* flags   = (unsigned*)(hist + (size_t)NROW_ * NB_);  // NROW*FW
    int*      cnt     = (int*)(flags + NROW_ * FW_);              // 32
    int4*     pick    = (int4*)(cnt + 32);                        // B*R int4
    unsigned* packed  = (unsigned*)(pick + B_ * R_);              // B*M
    int*      buckets = (int*)(packed + (size_t)B_ * M_);         // NROW*M
    float4*   gt4     = (float4*)(buckets + (size_t)NROW_ * M_);  // B*G
    float*    garea   = (float*)(gt4 + B_ * G_);                  // B*G
    int*      jmax    = (int*)(garea + B_ * G_);                  // B

    prep_kernel<<<512, TPB_, 0, stream>>>(gt_boxes, hist, gt4, garea, jmax);

    dim3 grid1((M_ + TPB_ - 1) / TPB_, B_);
    iou_kernel<<<grid1, TPB_, 0, stream>>>(all_rois, gt_boxes, gt4, garea, jmax,
                                           u_perm, packed, hist);
    scanflag_kernel<<<B_, 512, 0, stream>>>(hist, flags, cnt, u_fg, u_bg, pick);
    scatter_kernel<<<grid1, TPB_, 0, stream>>>(packed, flags, hist, buckets);
    sample_kernel<<<B_, R_, 0, stream>>>(all_rois, gt_boxes, gt4, garea, u_perm,
                                         cnt, pick, buckets, out);
}